// Round 4
// baseline (22055.661 us; speedup 1.0000x reference)
//
#include <hip/hip_runtime.h>

// LSTM: I=512, H=2048, O=512, T=4096, batch=1, fp32.
// Phase 1: xz[T][4H] = input @ W_ih^T + (b_ih + b_hh)   (tiled fp32 GEMM)
// Phase 2: persistent kernel, 256 blocks = 256 CUs, W_hh register-resident.
//          R12 = R10 (fused h|tag lines, single-store handshake) + DENSE TAG
//          SENTINEL. R10/R8 both re-pulled the FULL 4KB payload per wave on
//          EVERY poll iteration (~4MB device sweep, ~5 sweeps/step => the
//          dominant ~2.4us/step cost; R11 proved it isn't request-count
//          congestion). R12 splits the handshake:
//            Phase A: poll a dense u16 tag array (1024 waves x 2B): 8 cache
//                     lines per wave per iteration (8x cheaper sweeps), spin
//                     until all 256 source-wave tags >= t.
//            Phase B: R10's fused-line poll -- now typically ONE iteration,
//                     so the 4KB payload crosses the fabric once per step.
//          Dense tags are a HINT only; the fused-line tags (arriving with
//          the payload) remain the authoritative guard, so producer store
//          reordering between the two stores is harmless (Phase B re-polls).
//          Correctness skeleton == R10: tag monotone, per-8B {h,tag} tear
//          guard, parity overwrite safety via the staging barrier, sticky
//          degraded caps (fast wrong answer, never a container kill).
// Phase 3: out = W_lin @ h_T + b_lin (h_T gathered from parity-0 lines).

#define TSTEPS 4096
#define HDIM   2048
#define GDIM   8192   // 4H
#define IDIM   512
#define ODIM   512

#define XZ_BYTES ((size_t)TSTEPS * GDIM * sizeof(float))   // 128 MB

typedef int int4v __attribute__((ext_vector_type(4)));
typedef int int2v __attribute__((ext_vector_type(2)));

__device__ __forceinline__ float sigmoidf_fast(float x) {
    return 1.0f / (1.0f + __expf(-x));
}
__device__ __forceinline__ float tanhf_fast(float x) {
    return 2.0f / (1.0f + __expf(-2.0f * x)) - 1.0f;
}

// MALL-coherent (agent scope) accesses: sc0 sc1.
__device__ __forceinline__ void poll4_mall(const int4v* p0, const int4v* p1,
                                           const int4v* p2, const int4v* p3,
                                           int4v& a, int4v& b, int4v& c, int4v& d)
{
    asm volatile(
        "global_load_dwordx4 %0, %4, off sc0 sc1\n\t"
        "global_load_dwordx4 %1, %5, off sc0 sc1\n\t"
        "global_load_dwordx4 %2, %6, off sc0 sc1\n\t"
        "global_load_dwordx4 %3, %7, off sc0 sc1\n\t"
        "s_waitcnt vmcnt(0)"
        : "=&v"(a), "=&v"(b), "=&v"(c), "=&v"(d)
        : "v"(p0), "v"(p1), "v"(p2), "v"(p3)
        : "memory");
}
__device__ __forceinline__ int2v load_tags8(const unsigned short* p)
{
    int2v tv;
    asm volatile(
        "global_load_dwordx2 %0, %1, off sc0 sc1\n\t"
        "s_waitcnt vmcnt(0)"
        : "=&v"(tv) : "v"(p) : "memory");
    return tv;
}
__device__ __forceinline__ void store_line(int4v* p, int4v v)
{
    asm volatile("global_store_dwordx4 %0, %1, off sc0 sc1"
                 :: "v"(p), "v"(v) : "memory");
}
__device__ __forceinline__ void store_tag16(unsigned short* p, unsigned v)
{
    asm volatile("global_store_short %0, %1, off sc0 sc1"
                 :: "v"(p), "v"(v) : "memory");
}

__device__ __forceinline__ bool tags_ok(const int4v& v0, const int4v& v1,
                                        const int4v& v2, const int4v& v3,
                                        unsigned need)
{
    return ((unsigned)v0.y >= need) & ((unsigned)v0.w >= need) &
           ((unsigned)v1.y >= need) & ((unsigned)v1.w >= need) &
           ((unsigned)v2.y >= need) & ((unsigned)v2.w >= need) &
           ((unsigned)v3.y >= need) & ((unsigned)v3.w >= need);
}

// ---------------------------------------------------------------------------
// Phase 1: C[4096][8192] = A[4096][512] * B[8192][512]^T + (bih+bhh)[n]
// 128x128 block tile, BK=16, 256 threads, 8x8 per thread. (unchanged)
// ---------------------------------------------------------------------------
__global__ __launch_bounds__(256) void xz_gemm(
    const float* __restrict__ A, const float* __restrict__ B,
    const float* __restrict__ bih, const float* __restrict__ bhh,
    float* __restrict__ C)
{
    __shared__ float As[16][132];
    __shared__ float Bs[16][132];

    const int tid = threadIdx.x;
    const int m0 = blockIdx.y * 128;
    const int n0 = blockIdx.x * 128;
    const int tx = tid & 15;        // n-direction
    const int ty = tid >> 4;        // m-direction

    const int lrow  = tid >> 1;          // 0..127
    const int kbase = (tid & 1) * 8;     // k offset 0 or 8

    float acc[8][8] = {};

    for (int k0 = 0; k0 < IDIM; k0 += 16) {
        const float4 av0 = *(const float4*)(A + (size_t)(m0 + lrow) * IDIM + k0 + kbase);
        const float4 av1 = *(const float4*)(A + (size_t)(m0 + lrow) * IDIM + k0 + kbase + 4);
        const float4 bv0 = *(const float4*)(B + (size_t)(n0 + lrow) * IDIM + k0 + kbase);
        const float4 bv1 = *(const float4*)(B + (size_t)(n0 + lrow) * IDIM + k0 + kbase + 4);

        __syncthreads();   // previous tile fully consumed
        As[kbase + 0][lrow] = av0.x; As[kbase + 1][lrow] = av0.y;
        As[kbase + 2][lrow] = av0.z; As[kbase + 3][lrow] = av0.w;
        As[kbase + 4][lrow] = av1.x; As[kbase + 5][lrow] = av1.y;
        As[kbase + 6][lrow] = av1.z; As[kbase + 7][lrow] = av1.w;
        Bs[kbase + 0][lrow] = bv0.x; Bs[kbase + 1][lrow] = bv0.y;
        Bs[kbase + 2][lrow] = bv0.z; Bs[kbase + 3][lrow] = bv0.w;
        Bs[kbase + 4][lrow] = bv1.x; Bs[kbase + 5][lrow] = bv1.y;
        Bs[kbase + 6][lrow] = bv1.z; Bs[kbase + 7][lrow] = bv1.w;
        __syncthreads();

#pragma unroll
        for (int kk = 0; kk < 16; ++kk) {
            const float4 a0 = *(const float4*)&As[kk][ty * 8];
            const float4 a1 = *(const float4*)&As[kk][ty * 8 + 4];
            const float4 b0 = *(const float4*)&Bs[kk][tx * 8];
            const float4 b1 = *(const float4*)&Bs[kk][tx * 8 + 4];
            const float ar[8] = {a0.x, a0.y, a0.z, a0.w, a1.x, a1.y, a1.z, a1.w};
            const float br[8] = {b0.x, b0.y, b0.z, b0.w, b1.x, b1.y, b1.z, b1.w};
#pragma unroll
            for (int i = 0; i < 8; ++i)
#pragma unroll
                for (int jj = 0; jj < 8; ++jj)
                    acc[i][jj] = fmaf(ar[i], br[jj], acc[i][jj]);
        }
    }

    float bias[8];
#pragma unroll
    for (int jj = 0; jj < 8; ++jj) {
        const int n = n0 + tx * 8 + jj;
        bias[jj] = bih[n] + bhh[n];
    }
#pragma unroll
    for (int i = 0; i < 8; ++i) {
        float* crow = C + (size_t)(m0 + ty * 8 + i) * GDIM + n0 + tx * 8;
        float4 v0, v1;
        v0.x = acc[i][0] + bias[0]; v0.y = acc[i][1] + bias[1];
        v0.z = acc[i][2] + bias[2]; v0.w = acc[i][3] + bias[3];
        v1.x = acc[i][4] + bias[4]; v1.y = acc[i][5] + bias[5];
        v1.z = acc[i][6] + bias[6]; v1.w = acc[i][7] + bias[7];
        ((float4*)crow)[0] = v0;
        ((float4*)crow)[1] = v1;
    }
}

// ---------------------------------------------------------------------------
// Phase 2: persistent recurrent kernel. 256 blocks x 256 threads, 1 block/CU.
// tid -> j = tid>>5 (h index), gate = (tid>>3)&3 (i,f,g,o), chunk = tid&7.
// Wave w of block b produces h[8b+2w] (lane 0) and h[8b+2w+1] (lane 32);
// fused line 4b+w holds {h0, tag, h1, tag}, tag = steps done; dense tag
// tg[4b+w] (u16) mirrors the tag for cheap polling.
// Quarter q is produced by lines [256q, 256q+256); wave wv polls dense tags
// [256wv, 256wv+256) (4 u16 per lane, 8B) until all >= t, then pulls the
// payload lines (4 x dwordx4 per lane) -- typically once per step.
// lines[2][1024]: parity by step. Tags are monotone: no parity needed.
// ---------------------------------------------------------------------------
__global__ __launch_bounds__(256, 1) void lstm_rec(
    const float* __restrict__ Whh, const float* __restrict__ xz,
    int4v* __restrict__ lines, unsigned short* __restrict__ tg)
{
    // double-buffered h stage: 8 chunks x 260 (skew 4) per buffer ->
    // matvec ds_read_b128 stays bank-conflict-free.
    __shared__ float hsh[2 * 2080];

    const int tidb = threadIdx.x;
    const int tid  = blockIdx.x * 256 + tidb;
    const int j    = tid >> 5;
    const int g    = (tid >> 3) & 3;
    const int ck   = tid & 7;
    const int row  = g * HDIM + j;
    const int wv   = tidb >> 6;    // wave == h-quarter this wave handles
    const int ln   = tidb & 63;    // lane

    // one-time weight load into registers (64 MB total across grid)
    const float4* wsrc = (const float4*)(Whh + (size_t)row * HDIM + ck * 256);
    float4 w[64];
#pragma unroll
    for (int i = 0; i < 64; ++i) w[i] = wsrc[i];

    const bool owner = (tid & 31) == 0;
    float cstate = 0.0f;

    int4v*          sl0 = lines + (blockIdx.x * 4 + wv);   // my line, parity 0
    int4v*          sl1 = sl0 + 1024;                      // parity 1
    const int4v*    cb0 = lines + 256 * wv + ln;           // my quarter, parity 0
    const int4v*    cb1 = cb0 + 1024;
    unsigned short* myt = tg + (blockIdx.x * 4 + wv);      // my dense tag
    const unsigned short* qt = tg + 256 * wv + 4 * ln;     // quarter tags, 4/lane

    float zx = xz[row];   // xz[0][row]

    // caps: generous on first use, sticky-small after first timeout so a
    // stalled producer ends in a fast wrong answer, never a container kill.
    unsigned capA = 1u << 21;
    unsigned capB = 1u << 21;

    for (int t = 0; t < TSTEPS; ++t) {
        const unsigned need = (unsigned)t;

        // ---- Phase A: cheap dense-tag gate (8 lines/wave per iteration) ----
        {
            unsigned spins = 0;
            for (;;) {
                const int2v tv = load_tags8(qt);
                const unsigned a = (unsigned)tv.x, b = (unsigned)tv.y;
                const bool ok = ((a & 0xFFFFu) >= need) & ((a >> 16) >= need) &
                                ((b & 0xFFFFu) >= need) & ((b >> 16) >= need);
                if (__all(ok)) break;
                if (++spins > capA) { capA = 2048; break; }
            }
        }

        // ---- Phase B: one-shot payload pull (authoritative fused tags) ----
        int4v v0, v1, v2, v3;
        {
            const int4v* cb = (t & 1) ? cb1 : cb0;
            unsigned spins = 0;
            for (;;) {
                poll4_mall(cb, cb + 64, cb + 128, cb + 192, v0, v1, v2, v3);
                if (tags_ok(v0, v1, v2, v3, need)) break;
                __builtin_amdgcn_s_sleep(1);
                if (++spins > capB) { capB = 2048; break; }
            }
        }

        // ---- stage quarter: chunk 2wv/2wv+1 of the LDS h image ----
        const int buf = t & 1;
        const int b0  = buf * 2080 + (2 * wv) * 260;   // chunk 2wv
        const int b1  = b0 + 260;                      // chunk 2wv+1
        *(float2*)&hsh[b0 +       2 * ln] = make_float2(__int_as_float(v0.x), __int_as_float(v0.z));
        *(float2*)&hsh[b0 + 128 + 2 * ln] = make_float2(__int_as_float(v1.x), __int_as_float(v1.z));
        *(float2*)&hsh[b1 +       2 * ln] = make_float2(__int_as_float(v2.x), __int_as_float(v2.z));
        *(float2*)&hsh[b1 + 128 + 2 * ln] = make_float2(__int_as_float(v3.x), __int_as_float(v3.z));
        __syncthreads();   // only barrier in the step

        // xz prefetch for t+1: issued post-barrier, consumed next step ->
        // its latency is never on the handshake critical path.
        const int tn = (t + 1 < TSTEPS) ? (t + 1) : (TSTEPS - 1);
        const float zx_next = xz[(size_t)tn * GDIM + row];

        // ---- matvec from LDS (conflict-free b128 reads) ----
        const float4* hr = (const float4*)(hsh + buf * 2080 + ck * 260);
        float a0 = 0.f, a1 = 0.f, a2 = 0.f, a3 = 0.f;
#pragma unroll
        for (int i = 0; i < 64; ++i) {
            const float4 h4 = hr[i];
            a0 = fmaf(w[i].x, h4.x, a0);
            a1 = fmaf(w[i].y, h4.y, a1);
            a2 = fmaf(w[i].z, h4.z, a2);
            a3 = fmaf(w[i].w, h4.w, a3);
        }
        float d = (a0 + a1) + (a2 + a3);
        d += __shfl_xor(d, 1);
        d += __shfl_xor(d, 2);
        d += __shfl_xor(d, 4);
        const float z  = d + zx;
        const float zf = __shfl_xor(z, 8);    // gate f partner
        const float zg = __shfl_xor(z, 16);   // gate g partner
        const float zo = __shfl_xor(z, 24);   // gate o partner

        float hval = 0.0f;
        if (owner) {   // lanes 0 and 32 of the wave
            const float ig = sigmoidf_fast(z);
            const float fg = sigmoidf_fast(zf);
            const float gg = tanhf_fast(zg);
            const float og = sigmoidf_fast(zo);
            cstate = fmaf(fg, cstate, ig * gg);
            hval = og * tanhf_fast(cstate);
        }
        const float h1 = __shfl(hval, 32);   // lane 32's h into all lanes
        if (ln == 0) {
            // fused line first (payload + authoritative tag, tear-safe per
            // 8B half), then the dense hint tag. No drain needed: Phase B
            // re-polls if the hint outruns the payload.
            int4v sv;
            sv.x = __float_as_int(hval); sv.y = t + 1;
            sv.z = __float_as_int(h1);   sv.w = t + 1;
            store_line(((t + 1) & 1) ? sl1 : sl0, sv);
            store_tag16(myt, (unsigned)(t + 1));
        }
        zx = zx_next;
    }
}

// ---------------------------------------------------------------------------
// Phase 3: out[512] = W_lin[512][2048] @ h_T + b_lin. One wave per output.
// h_T lives interleaved in parity-0 global lines. (T=4096 even -> parity 0.)
// ---------------------------------------------------------------------------
__global__ __launch_bounds__(256) void final_linear(
    const float* __restrict__ Wlin, const float* __restrict__ blin,
    const int4v* __restrict__ hl, float* __restrict__ out)
{
    const int wid  = (blockIdx.x * 256 + threadIdx.x) >> 6;   // 0..511
    const int lane = threadIdx.x & 63;
    const float4* wr = (const float4*)(Wlin + (size_t)wid * HDIM);
    float acc = 0.f;
#pragma unroll
    for (int i = 0; i < 8; ++i) {
        const int k = lane + 64 * i;          // float4 index into h
        const float4 w4 = wr[k];
        const int4v la = hl[2 * k];           // {h[4k],   tag, h[4k+1], tag}
        const int4v lb = hl[2 * k + 1];       // {h[4k+2], tag, h[4k+3], tag}
        acc += w4.x * __int_as_float(la.x) + w4.y * __int_as_float(la.z)
             + w4.z * __int_as_float(lb.x) + w4.w * __int_as_float(lb.z);
    }
#pragma unroll
    for (int off = 32; off > 0; off >>= 1) acc += __shfl_down(acc, off);
    if (lane == 0) out[wid] = acc + blin[wid];
}

extern "C" void kernel_launch(void* const* d_in, const int* in_sizes, int n_in,
                              void* d_out, int out_size, void* d_ws, size_t ws_size,
                              hipStream_t stream) {
    const float* input = (const float*)d_in[0];   // [4096][512]
    const float* Wih   = (const float*)d_in[1];   // [8192][512]
    const float* Whh   = (const float*)d_in[2];   // [8192][2048]
    const float* bih   = (const float*)d_in[3];   // [8192]
    const float* bhh   = (const float*)d_in[4];   // [8192]
    const float* Wlin  = (const float*)d_in[5];   // [512][2048]
    const float* blin  = (const float*)d_in[6];   // [512]
    float* out = (float*)d_out;                   // [512]

    char* ws = (char*)d_ws;
    float*          xz    = (float*)ws;                       // 128 MB
    int4v*          lines = (int4v*)(ws + XZ_BYTES);          // 2*1024*16B = 32 KB
    unsigned short* tg    = (unsigned short*)(ws + XZ_BYTES + 32768);  // 2 KB

    // zero lines + dense tags (tag 0 == h_0 = zeros valid everywhere).
    hipMemsetAsync(lines, 0, 32768 + 4096, stream);

    dim3 ggrid(GDIM / 128, TSTEPS / 128);   // (64, 32)
    xz_gemm<<<ggrid, 256, 0, stream>>>(input, Wih, bih, bhh, xz);

    // plain launch: 256 blocks, 1 block/CU => all co-resident on 256 CUs.
    lstm_rec<<<dim3(256), dim3(256), 0, stream>>>(Whh, xz, lines, tg);

    final_linear<<<ODIM / 4, 256, 0, stream>>>(Wlin, blin, lines, out);
}

// Round 5
// 16202.425 us; speedup vs baseline: 1.3613x; 1.3613x over previous
//
#include <hip/hip_runtime.h>

// LSTM: I=512, H=2048, O=512, T=4096, batch=1, fp32.
// Phase 1: xz[T][4H] = input @ W_ih^T + (b_ih + b_hh)   (tiled fp32 GEMM)
// Phase 2: persistent kernel, 256 blocks = 256 CUs, W_hh register-resident.
//          R13 = R10 (fused h|tag lines, ONE-hop handshake -- best measured,
//          16.0ms) + serial-path cuts. R11/R12 established: handshake cost =
//          hops x iterations x RT, independent of polled bytes; R10's single
//          hop is minimal. R13 shortens the iteration period and the
//          producer path:
//           (1) 2-deep pipelined poll: two 4-load generations in flight;
//               each asm block issues gen-next and s_waitcnt vmcnt(4)s
//               gen-prev (4 newest outstanding == in-flight gen, so the
//               count is exact under any older outstanding store/prefetch;
//               "memory" clobbers keep compiler VMEM out; drain8 pins all
//               8 regs before the selects so late-landing loads can't
//               clobber reused registers).
//           (2) no s_sleep on the fast path (only after 64 failed iters).
//           (3) producer: lanes 0 AND 32 each store their own 8B {h, tag}
//               half (one global_store_dwordx2, same 16B line -> coalesced);
//               drops the final __shfl from the critical path. Per-8B
//               tear-guard semantics unchanged.
//          Correctness skeleton == R10: tag monotone, parity double-buffer,
//          staging barrier => max skew 1 step, sticky degraded caps (fast
//          wrong answer, never a container kill).
// Phase 3: out = W_lin @ h_T + b_lin (h_T gathered from parity-0 lines).

#define TSTEPS 4096
#define HDIM   2048
#define GDIM   8192   // 4H
#define IDIM   512
#define ODIM   512

#define XZ_BYTES ((size_t)TSTEPS * GDIM * sizeof(float))   // 128 MB

typedef int int4v __attribute__((ext_vector_type(4)));
typedef int int2v __attribute__((ext_vector_type(2)));

__device__ __forceinline__ float sigmoidf_fast(float x) {
    return 1.0f / (1.0f + __expf(-x));
}
__device__ __forceinline__ float tanhf_fast(float x) {
    return 2.0f / (1.0f + __expf(-2.0f * x)) - 1.0f;
}

// Issue one 4-load generation (agent-coherent, no wait).
__device__ __forceinline__ void issue4(const int4v* p0, const int4v* p1,
                                       const int4v* p2, const int4v* p3,
                                       int4v& a, int4v& b, int4v& c, int4v& d)
{
    asm volatile(
        "global_load_dwordx4 %0, %4, off sc0 sc1\n\t"
        "global_load_dwordx4 %1, %5, off sc0 sc1\n\t"
        "global_load_dwordx4 %2, %6, off sc0 sc1\n\t"
        "global_load_dwordx4 %3, %7, off sc0 sc1"
        : "=&v"(a), "=&v"(b), "=&v"(c), "=&v"(d)
        : "v"(p0), "v"(p1), "v"(p2), "v"(p3)
        : "memory");
}
// Issue the next generation, then wait until only those 4 newest loads are
// outstanding -> everything older (prev gen + producer store + prefetches)
// has landed. Prev-gen regs are "+v" inouts: pins them and sequences the
// C-level tag check AFTER this block.
__device__ __forceinline__ void issue4_wait4(
    const int4v* p0, const int4v* p1, const int4v* p2, const int4v* p3,
    int4v& n0, int4v& n1, int4v& n2, int4v& n3,
    int4v& o0, int4v& o1, int4v& o2, int4v& o3)
{
    asm volatile(
        "global_load_dwordx4 %0, %8, off sc0 sc1\n\t"
        "global_load_dwordx4 %1, %9, off sc0 sc1\n\t"
        "global_load_dwordx4 %2, %10, off sc0 sc1\n\t"
        "global_load_dwordx4 %3, %11, off sc0 sc1\n\t"
        "s_waitcnt vmcnt(4)"
        : "=&v"(n0), "=&v"(n1), "=&v"(n2), "=&v"(n3),
          "+v"(o0), "+v"(o1), "+v"(o2), "+v"(o3)
        : "v"(p0), "v"(p1), "v"(p2), "v"(p3)
        : "memory");
}
// Retire ALL outstanding VMEM while pinning both generations' registers:
// no in-flight load can land into a register the allocator has reused.
__device__ __forceinline__ void drain8(int4v& a0, int4v& a1, int4v& a2, int4v& a3,
                                       int4v& b0, int4v& b1, int4v& b2, int4v& b3)
{
    asm volatile("s_waitcnt vmcnt(0)"
                 : "+v"(a0), "+v"(a1), "+v"(a2), "+v"(a3),
                   "+v"(b0), "+v"(b1), "+v"(b2), "+v"(b3)
                 :: "memory");
}
__device__ __forceinline__ void store_half(void* p, int2v v)
{
    asm volatile("global_store_dwordx2 %0, %1, off sc0 sc1"
                 :: "v"(p), "v"(v) : "memory");
}

__device__ __forceinline__ bool tags_ok(const int4v& v0, const int4v& v1,
                                        const int4v& v2, const int4v& v3,
                                        unsigned need)
{
    return ((unsigned)v0.y >= need) & ((unsigned)v0.w >= need) &
           ((unsigned)v1.y >= need) & ((unsigned)v1.w >= need) &
           ((unsigned)v2.y >= need) & ((unsigned)v2.w >= need) &
           ((unsigned)v3.y >= need) & ((unsigned)v3.w >= need);
}

// ---------------------------------------------------------------------------
// Phase 1: C[4096][8192] = A[4096][512] * B[8192][512]^T + (bih+bhh)[n]
// 128x128 block tile, BK=16, 256 threads, 8x8 per thread. (unchanged)
// ---------------------------------------------------------------------------
__global__ __launch_bounds__(256) void xz_gemm(
    const float* __restrict__ A, const float* __restrict__ B,
    const float* __restrict__ bih, const float* __restrict__ bhh,
    float* __restrict__ C)
{
    __shared__ float As[16][132];
    __shared__ float Bs[16][132];

    const int tid = threadIdx.x;
    const int m0 = blockIdx.y * 128;
    const int n0 = blockIdx.x * 128;
    const int tx = tid & 15;        // n-direction
    const int ty = tid >> 4;        // m-direction

    const int lrow  = tid >> 1;          // 0..127
    const int kbase = (tid & 1) * 8;     // k offset 0 or 8

    float acc[8][8] = {};

    for (int k0 = 0; k0 < IDIM; k0 += 16) {
        const float4 av0 = *(const float4*)(A + (size_t)(m0 + lrow) * IDIM + k0 + kbase);
        const float4 av1 = *(const float4*)(A + (size_t)(m0 + lrow) * IDIM + k0 + kbase + 4);
        const float4 bv0 = *(const float4*)(B + (size_t)(n0 + lrow) * IDIM + k0 + kbase);
        const float4 bv1 = *(const float4*)(B + (size_t)(n0 + lrow) * IDIM + k0 + kbase + 4);

        __syncthreads();   // previous tile fully consumed
        As[kbase + 0][lrow] = av0.x; As[kbase + 1][lrow] = av0.y;
        As[kbase + 2][lrow] = av0.z; As[kbase + 3][lrow] = av0.w;
        As[kbase + 4][lrow] = av1.x; As[kbase + 5][lrow] = av1.y;
        As[kbase + 6][lrow] = av1.z; As[kbase + 7][lrow] = av1.w;
        Bs[kbase + 0][lrow] = bv0.x; Bs[kbase + 1][lrow] = bv0.y;
        Bs[kbase + 2][lrow] = bv0.z; Bs[kbase + 3][lrow] = bv0.w;
        Bs[kbase + 4][lrow] = bv1.x; Bs[kbase + 5][lrow] = bv1.y;
        Bs[kbase + 6][lrow] = bv1.z; Bs[kbase + 7][lrow] = bv1.w;
        __syncthreads();

#pragma unroll
        for (int kk = 0; kk < 16; ++kk) {
            const float4 a0 = *(const float4*)&As[kk][ty * 8];
            const float4 a1 = *(const float4*)&As[kk][ty * 8 + 4];
            const float4 b0 = *(const float4*)&Bs[kk][tx * 8];
            const float4 b1 = *(const float4*)&Bs[kk][tx * 8 + 4];
            const float ar[8] = {a0.x, a0.y, a0.z, a0.w, a1.x, a1.y, a1.z, a1.w};
            const float br[8] = {b0.x, b0.y, b0.z, b0.w, b1.x, b1.y, b1.z, b1.w};
#pragma unroll
            for (int i = 0; i < 8; ++i)
#pragma unroll
                for (int jj = 0; jj < 8; ++jj)
                    acc[i][jj] = fmaf(ar[i], br[jj], acc[i][jj]);
        }
    }

    float bias[8];
#pragma unroll
    for (int jj = 0; jj < 8; ++jj) {
        const int n = n0 + tx * 8 + jj;
        bias[jj] = bih[n] + bhh[n];
    }
#pragma unroll
    for (int i = 0; i < 8; ++i) {
        float* crow = C + (size_t)(m0 + ty * 8 + i) * GDIM + n0 + tx * 8;
        float4 v0, v1;
        v0.x = acc[i][0] + bias[0]; v0.y = acc[i][1] + bias[1];
        v0.z = acc[i][2] + bias[2]; v0.w = acc[i][3] + bias[3];
        v1.x = acc[i][4] + bias[4]; v1.y = acc[i][5] + bias[5];
        v1.z = acc[i][6] + bias[6]; v1.w = acc[i][7] + bias[7];
        ((float4*)crow)[0] = v0;
        ((float4*)crow)[1] = v1;
    }
}

// ---------------------------------------------------------------------------
// Phase 2: persistent recurrent kernel. 256 blocks x 256 threads, 1 block/CU.
// tid -> j = tid>>5 (h index), gate = (tid>>3)&3 (i,f,g,o), chunk = tid&7.
// Wave w of block b produces h[8b+2w] (lane 0) and h[8b+2w+1] (lane 32);
// fused line 4b+w holds {h0, tag, h1, tag}, tag = steps done. Quarter q of h
// is produced by lines [256q, 256q+256); wave wv polls exactly those 256
// lines (4 coalesced dwordx4 per lane, 2-deep pipelined) and receives the
// h payload in the detecting load. lines[2][1024]: parity by step.
// ---------------------------------------------------------------------------
__global__ __launch_bounds__(256, 1) void lstm_rec(
    const float* __restrict__ Whh, const float* __restrict__ xz,
    int4v* __restrict__ lines)
{
    // double-buffered h stage: 8 chunks x 260 (skew 4) per buffer ->
    // matvec ds_read_b128 stays bank-conflict-free.
    __shared__ float hsh[2 * 2080];

    const int tidb = threadIdx.x;
    const int tid  = blockIdx.x * 256 + tidb;
    const int j    = tid >> 5;
    const int g    = (tid >> 3) & 3;
    const int ck   = tid & 7;
    const int row  = g * HDIM + j;
    const int wv   = tidb >> 6;    // wave == h-quarter this wave handles
    const int ln   = tidb & 63;    // lane

    // one-time weight load into registers (64 MB total across grid)
    const float4* wsrc = (const float4*)(Whh + (size_t)row * HDIM + ck * 256);
    float4 w[64];
#pragma unroll
    for (int i = 0; i < 64; ++i) w[i] = wsrc[i];

    const bool owner = (tid & 31) == 0;
    float cstate = 0.0f;

    int4v*       sl0 = lines + (blockIdx.x * 4 + wv);   // my line, parity 0
    int4v*       sl1 = sl0 + 1024;                      // parity 1
    const int4v* cb0 = lines + 256 * wv + ln;           // my quarter, parity 0
    const int4v* cb1 = cb0 + 1024;

    float zx = xz[row];   // xz[0][row]

    // Degraded-mode cap: generous first, sticky-small after a timeout so a
    // stalled producer yields a fast wrong answer, never a container kill.
    unsigned cap = 1u << 21;

    for (int t = 0; t < TSTEPS; ++t) {
        const unsigned need = (unsigned)t;

        // ---- leading wait + h receive: 2-deep pipelined one-hop poll ----
        int4v A0, A1, A2, A3, B0, B1, B2, B3;
        bool useB = false;
        {
            const int4v* cb = (t & 1) ? cb1 : cb0;
            issue4(cb, cb + 64, cb + 128, cb + 192, A0, A1, A2, A3);
            __builtin_amdgcn_sched_barrier(0);
            unsigned spins = 0;
            for (;;) {
                // issue gen B, wait gen A (everything older also landed)
                issue4_wait4(cb, cb + 64, cb + 128, cb + 192,
                             B0, B1, B2, B3, A0, A1, A2, A3);
                __builtin_amdgcn_sched_barrier(0);
                if (tags_ok(A0, A1, A2, A3, need)) { useB = false; break; }
                if (++spins > cap) { cap = 2048; useB = false; break; }
                if (spins > 64) __builtin_amdgcn_s_sleep(1);
                // issue gen A, wait gen B
                issue4_wait4(cb, cb + 64, cb + 128, cb + 192,
                             A0, A1, A2, A3, B0, B1, B2, B3);
                __builtin_amdgcn_sched_barrier(0);
                if (tags_ok(B0, B1, B2, B3, need)) { useB = true; break; }
                if (++spins > cap) { cap = 2048; useB = true; break; }
                if (spins > 64) __builtin_amdgcn_s_sleep(1);
            }
        }
        // retire stragglers with both generations' registers pinned, THEN
        // select the winning generation (per-lane).
        drain8(A0, A1, A2, A3, B0, B1, B2, B3);
        const int4v v0 = useB ? B0 : A0;
        const int4v v1 = useB ? B1 : A1;
        const int4v v2 = useB ? B2 : A2;
        const int4v v3 = useB ? B3 : A3;

        // ---- stage quarter: chunk 2wv/2wv+1 of the LDS h image ----
        const int buf = t & 1;
        const int b0  = buf * 2080 + (2 * wv) * 260;   // chunk 2wv
        const int b1  = b0 + 260;                      // chunk 2wv+1
        *(float2*)&hsh[b0 +       2 * ln] = make_float2(__int_as_float(v0.x), __int_as_float(v0.z));
        *(float2*)&hsh[b0 + 128 + 2 * ln] = make_float2(__int_as_float(v1.x), __int_as_float(v1.z));
        *(float2*)&hsh[b1 +       2 * ln] = make_float2(__int_as_float(v2.x), __int_as_float(v2.z));
        *(float2*)&hsh[b1 + 128 + 2 * ln] = make_float2(__int_as_float(v3.x), __int_as_float(v3.z));
        __syncthreads();   // only barrier in the step

        // xz prefetch for t+1: issued post-barrier, consumed next step ->
        // its latency is never on the handshake critical path.
        const int tn = (t + 1 < TSTEPS) ? (t + 1) : (TSTEPS - 1);
        const float zx_next = xz[(size_t)tn * GDIM + row];

        // ---- matvec from LDS (conflict-free b128 reads) ----
        const float4* hr = (const float4*)(hsh + buf * 2080 + ck * 260);
        float a0 = 0.f, a1 = 0.f, a2 = 0.f, a3 = 0.f;
#pragma unroll
        for (int i = 0; i < 64; ++i) {
            const float4 h4 = hr[i];
            a0 = fmaf(w[i].x, h4.x, a0);
            a1 = fmaf(w[i].y, h4.y, a1);
            a2 = fmaf(w[i].z, h4.z, a2);
            a3 = fmaf(w[i].w, h4.w, a3);
        }
        float d = (a0 + a1) + (a2 + a3);
        d += __shfl_xor(d, 1);
        d += __shfl_xor(d, 2);
        d += __shfl_xor(d, 4);
        const float z  = d + zx;
        const float zf = __shfl_xor(z, 8);    // gate f partner
        const float zg = __shfl_xor(z, 16);   // gate g partner
        const float zo = __shfl_xor(z, 24);   // gate o partner

        if (owner) {   // lanes 0 and 32 of the wave
            const float ig = sigmoidf_fast(z);
            const float fg = sigmoidf_fast(zf);
            const float gg = tanhf_fast(zg);
            const float og = sigmoidf_fast(zo);
            cstate = fmaf(fg, cstate, ig * gg);
            const float hval = og * tanhf_fast(cstate);
            // each owner lane stores its OWN 8B {h, tag} half of the 16B
            // line (lane0 -> bytes [0,8), lane32 -> [8,16); coalesces into
            // one transaction). No shuffle, no drain, no 2nd sync.
            int2v sv;
            sv.x = __float_as_int(hval);
            sv.y = (int)(t + 1);
            char* base = (char*)(((t + 1) & 1) ? sl1 : sl0);
            store_half(base + ((ln >> 5) << 3), sv);
        }
        zx = zx_next;
    }
}

// ---------------------------------------------------------------------------
// Phase 3: out[512] = W_lin[512][2048] @ h_T + b_lin. One wave per output.
// h_T lives interleaved in parity-0 global lines. (T=4096 even -> parity 0.)
// ---------------------------------------------------------------------------
__global__ __launch_bounds__(256) void final_linear(
    const float* __restrict__ Wlin, const float* __restrict__ blin,
    const int4v* __restrict__ hl, float* __restrict__ out)
{
    const int wid  = (blockIdx.x * 256 + threadIdx.x) >> 6;   // 0..511
    const int lane = threadIdx.x & 63;
    const float4* wr = (const float4*)(Wlin + (size_t)wid * HDIM);
    float acc = 0.f;
#pragma unroll
    for (int i = 0; i < 8; ++i) {
        const int k = lane + 64 * i;          // float4 index into h
        const float4 w4 = wr[k];
        const int4v la = hl[2 * k];           // {h[4k],   tag, h[4k+1], tag}
        const int4v lb = hl[2 * k + 1];       // {h[4k+2], tag, h[4k+3], tag}
        acc += w4.x * __int_as_float(la.x) + w4.y * __int_as_float(la.z)
             + w4.z * __int_as_float(lb.x) + w4.w * __int_as_float(lb.z);
    }
#pragma unroll
    for (int off = 32; off > 0; off >>= 1) acc += __shfl_down(acc, off);
    if (lane == 0) out[wid] = acc + blin[wid];
}

extern "C" void kernel_launch(void* const* d_in, const int* in_sizes, int n_in,
                              void* d_out, int out_size, void* d_ws, size_t ws_size,
                              hipStream_t stream) {
    const float* input = (const float*)d_in[0];   // [4096][512]
    const float* Wih   = (const float*)d_in[1];   // [8192][512]
    const float* Whh   = (const float*)d_in[2];   // [8192][2048]
    const float* bih   = (const float*)d_in[3];   // [8192]
    const float* bhh   = (const float*)d_in[4];   // [8192]
    const float* Wlin  = (const float*)d_in[5];   // [512][2048]
    const float* blin  = (const float*)d_in[6];   // [512]
    float* out = (float*)d_out;                   // [512]

    char* ws = (char*)d_ws;
    float* xz    = (float*)ws;                       // 128 MB
    int4v* lines = (int4v*)(ws + XZ_BYTES);          // 2 x 1024 x 16 B = 32 KB

    // zero fused lines (tag 0 == "0 steps done" == h_0 = zeros valid).
    hipMemsetAsync(lines, 0, 2 * 1024 * sizeof(int4v), stream);

    dim3 ggrid(GDIM / 128, TSTEPS / 128);   // (64, 32)
    xz_gemm<<<ggrid, 256, 0, stream>>>(input, Wih, bih, bhh, xz);

    // plain launch: 256 blocks, 1 block/CU => all co-resident on 256 CUs.
    lstm_rec<<<dim3(256), dim3(256), 0, stream>>>(Whh, xz, lines);

    final_linear<<<ODIM / 4, 256, 0, stream>>>(Wlin, blin, lines, out);
}